// Round 1
// baseline (1468.033 us; speedup 1.0000x reference)
//
#include <hip/hip_runtime.h>

#define BATCH 8192
#define T_PRIOR 168
#define N_FEAT 11
#define DEC_FEAT 7
#define HID 64
#define T_DEC 48
#define ROWS_PER_BLOCK 4

__device__ __forceinline__ float sigm(float x) { return 1.0f / (1.0f + __expf(-x)); }
__device__ __forceinline__ float tanhfast(float x) { return 2.0f / (1.0f + __expf(-2.0f * x)) - 1.0f; }

// h @ Whh.T accumulation: lane j holds Whh rows {j, 64+j, 128+j} in whh[0..2][..];
// h is broadcast from every lane via __shfl (compile-time lane index).
__device__ __forceinline__ void hh_matvec(const float4 (&whh)[3][16], float h,
                                          float& aR, float& aZ, float& aHN) {
#pragma unroll
    for (int k = 0; k < 16; ++k) {
        float h0 = __shfl(h, 4 * k + 0, 64);
        float h1 = __shfl(h, 4 * k + 1, 64);
        float h2 = __shfl(h, 4 * k + 2, 64);
        float h3 = __shfl(h, 4 * k + 3, 64);
        aR = fmaf(whh[0][k].x, h0, aR);
        aR = fmaf(whh[0][k].y, h1, aR);
        aR = fmaf(whh[0][k].z, h2, aR);
        aR = fmaf(whh[0][k].w, h3, aR);
        aZ = fmaf(whh[1][k].x, h0, aZ);
        aZ = fmaf(whh[1][k].y, h1, aZ);
        aZ = fmaf(whh[1][k].z, h2, aZ);
        aZ = fmaf(whh[1][k].w, h3, aZ);
        aHN = fmaf(whh[2][k].x, h0, aHN);
        aHN = fmaf(whh[2][k].y, h1, aHN);
        aHN = fmaf(whh[2][k].z, h2, aHN);
        aHN = fmaf(whh[2][k].w, h3, aHN);
    }
}

__global__ __launch_bounds__(256, 2)
void gru_seq2seq(const float* __restrict__ prior,
                 const float* __restrict__ teacher,
                 const float* __restrict__ eWih, const float* __restrict__ eWhh,
                 const float* __restrict__ eBih, const float* __restrict__ eBhh,
                 const float* __restrict__ dWih, const float* __restrict__ dWhh,
                 const float* __restrict__ dBih, const float* __restrict__ dBhh,
                 const float* __restrict__ fcW, const float* __restrict__ fcB,
                 float* __restrict__ out)
{
    __shared__ float4 sPrior4[ROWS_PER_BLOCK * T_PRIOR * N_FEAT / 4];   // 1848 f4
    __shared__ float4 sTeach4[ROWS_PER_BLOCK * T_DEC * DEC_FEAT / 4];   // 336 f4
    __shared__ float  sWihE[3 * HID * N_FEAT];                          // 2112 f
    __shared__ float  sWihD[3 * HID * DEC_FEAT];                        // 1344 f
    __shared__ float  sPred[ROWS_PER_BLOCK][T_DEC];

    const int tid  = (int)threadIdx.x;
    const int w    = tid >> 6;     // wave id within block = row within block
    const int lane = tid & 63;     // hidden unit
    const int row0 = (int)blockIdx.x * ROWS_PER_BLOCK;

    // ---- stage inputs (block's 4 rows are contiguous in memory) ----
    {
        const float4* gp = (const float4*)(prior + (size_t)row0 * (T_PRIOR * N_FEAT));
        for (int i = tid; i < ROWS_PER_BLOCK * T_PRIOR * N_FEAT / 4; i += 256) sPrior4[i] = gp[i];
        const float4* gt = (const float4*)(teacher + (size_t)row0 * (T_DEC * DEC_FEAT));
        for (int i = tid; i < ROWS_PER_BLOCK * T_DEC * DEC_FEAT / 4; i += 256) sTeach4[i] = gt[i];
        for (int i = tid; i < 3 * HID * N_FEAT; i += 256) sWihE[i] = eWih[i];
        for (int i = tid; i < 3 * HID * DEC_FEAT; i += 256) sWihD[i] = dWih[i];
    }
    __syncthreads();

    // ---- encoder weights: Whh rows for this lane's 3 gates into VGPRs ----
    float4 whh[3][16];
#pragma unroll
    for (int g = 0; g < 3; ++g) {
        const float4* wr = (const float4*)(eWhh + (size_t)(g * HID + lane) * HID);
#pragma unroll
        for (int k = 0; k < 16; ++k) whh[g][k] = wr[k];
    }
    float br  = eBih[lane] + eBhh[lane];
    float bz  = eBih[HID + lane] + eBhh[HID + lane];
    float biN = eBih[2 * HID + lane];
    float bhN = eBhh[2 * HID + lane];

    const float* sPriorW = ((const float*)sPrior4) + w * (T_PRIOR * N_FEAT);
    const float* sTeachW = ((const float*)sTeach4) + w * (T_DEC * DEC_FEAT);

    float h = 0.0f;

    // ---- encoder: 168 steps ----
    for (int t = 0; t < T_PRIOR; ++t) {
        float aR = br, aZ = bz, aIN = biN, aHN = bhN;
        const float* xp = sPriorW + t * N_FEAT;
#pragma unroll
        for (int f = 0; f < N_FEAT; ++f) {
            float xf = xp[f];
            aR  = fmaf(sWihE[(0 * HID + lane) * N_FEAT + f], xf, aR);
            aZ  = fmaf(sWihE[(1 * HID + lane) * N_FEAT + f], xf, aZ);
            aIN = fmaf(sWihE[(2 * HID + lane) * N_FEAT + f], xf, aIN);
        }
        hh_matvec(whh, h, aR, aZ, aHN);
        float r = sigm(aR), z = sigm(aZ);
        float n = tanhfast(fmaf(r, aHN, aIN));
        h = fmaf(z, h - n, n);   // (1-z)*n + z*h
    }

    // ---- decoder weights (reuse the same registers) ----
#pragma unroll
    for (int g = 0; g < 3; ++g) {
        const float4* wr = (const float4*)(dWhh + (size_t)(g * HID + lane) * HID);
#pragma unroll
        for (int k = 0; k < 16; ++k) whh[g][k] = wr[k];
    }
    br  = dBih[lane] + dBhh[lane];
    bz  = dBih[HID + lane] + dBhh[HID + lane];
    biN = dBih[2 * HID + lane];
    bhN = dBhh[2 * HID + lane];
    const float fw = fcW[lane];
    const float fb = fcB[0];

    // x0 = teacher_seq[:, 0, :]
    float xv[DEC_FEAT];
#pragma unroll
    for (int f = 0; f < DEC_FEAT; ++f) xv[f] = sTeachW[f];

    // ---- decoder: 48 steps, autoregressive on feature 4 ----
    for (int t = 0; t < T_DEC; ++t) {
        float aR = br, aZ = bz, aIN = biN, aHN = bhN;
#pragma unroll
        for (int f = 0; f < DEC_FEAT; ++f) {
            float xf = xv[f];
            aR  = fmaf(sWihD[(0 * HID + lane) * DEC_FEAT + f], xf, aR);
            aZ  = fmaf(sWihD[(1 * HID + lane) * DEC_FEAT + f], xf, aZ);
            aIN = fmaf(sWihD[(2 * HID + lane) * DEC_FEAT + f], xf, aIN);
        }
        hh_matvec(whh, h, aR, aZ, aHN);
        float r = sigm(aR), z = sigm(aZ);
        float n = tanhfast(fmaf(r, aHN, aIN));
        h = fmaf(z, h - n, n);

        // pred = h @ fc_W.T + fc_b  (full-wave reduction; result uniform)
        float p = h * fw;
#pragma unroll
        for (int off = 32; off >= 1; off >>= 1) p += __shfl_xor(p, off, 64);
        float pred = p + fb;
        if (lane == 0) sPred[w][t] = pred;

        // next x: [tn_t[0:4], pred, tn_t[5:7]] where tn_t = teacher[:, t+1, :] (zeros at t=47)
        if (t < T_DEC - 1) {
#pragma unroll
            for (int f = 0; f < DEC_FEAT; ++f) xv[f] = sTeachW[(t + 1) * DEC_FEAT + f];
            xv[4] = pred;
        }
    }

    __syncthreads();
    // out shape (B, T_DEC): out[b*48 + t]
    for (int i = tid; i < ROWS_PER_BLOCK * T_DEC; i += 256) {
        int w2 = i / T_DEC, t2 = i % T_DEC;
        out[(size_t)(row0 + w2) * T_DEC + t2] = sPred[w2][t2];
    }
}

extern "C" void kernel_launch(void* const* d_in, const int* in_sizes, int n_in,
                              void* d_out, int out_size, void* d_ws, size_t ws_size,
                              hipStream_t stream)
{
    const float* prior   = (const float*)d_in[0];
    const float* teacher = (const float*)d_in[1];
    const float* eWih    = (const float*)d_in[2];
    const float* eWhh    = (const float*)d_in[3];
    const float* eBih    = (const float*)d_in[4];
    const float* eBhh    = (const float*)d_in[5];
    const float* dWih    = (const float*)d_in[6];
    const float* dWhh    = (const float*)d_in[7];
    const float* dBih    = (const float*)d_in[8];
    const float* dBhh    = (const float*)d_in[9];
    const float* fcW     = (const float*)d_in[10];
    const float* fcB     = (const float*)d_in[11];
    float* out = (float*)d_out;

    dim3 grid(BATCH / ROWS_PER_BLOCK);   // 2048 blocks
    dim3 block(256);
    hipLaunchKernelGGL(gru_seq2seq, grid, block, 0, stream,
                       prior, teacher, eWih, eWhh, eBih, eBhh,
                       dWih, dWhh, dBih, dBhh, fcW, fcB, out);
}

// Round 2
// 793.656 us; speedup vs baseline: 1.8497x; 1.8497x over previous
//
#include <hip/hip_runtime.h>

#define BATCH 8192
#define T_PRIOR 168
#define N_FEAT 11
#define PF 12          // padded prior feature stride in LDS (float4-aligned)
#define DEC_FEAT 7
#define TF 8           // padded teacher stride in LDS
#define HID 64
#define T_DEC 48
#define RPB 4          // batch rows per block (1 per wave)

__device__ __forceinline__ float sigm(float x) { return 1.0f / (1.0f + __expf(-x)); }
__device__ __forceinline__ float tanhfast(float x) { return 2.0f / (1.0f + __expf(-2.0f * x)) - 1.0f; }

__device__ __forceinline__ float dot4(float4 a, float4 b, float acc) {
    acc = fmaf(a.x, b.x, acc);
    acc = fmaf(a.y, b.y, acc);
    acc = fmaf(a.z, b.z, acc);
    acc = fmaf(a.w, b.w, acc);
    return acc;
}

__global__ __launch_bounds__(256) __attribute__((amdgpu_waves_per_eu(2, 2)))
void gru_seq2seq(const float* __restrict__ prior,
                 const float* __restrict__ teacher,
                 const float* __restrict__ eWih, const float* __restrict__ eWhh,
                 const float* __restrict__ eBih, const float* __restrict__ eBhh,
                 const float* __restrict__ dWih, const float* __restrict__ dWhh,
                 const float* __restrict__ dBih, const float* __restrict__ dBhh,
                 const float* __restrict__ fcW, const float* __restrict__ fcB,
                 float* __restrict__ out)
{
    __shared__ float sPrior[RPB][T_PRIOR * PF];   // 4 x 2016 f = 32.3 KB
    __shared__ float sTeach[RPB][T_DEC * TF];     // 4 x 384 f  = 6.1 KB
    __shared__ float sH[RPB][HID];                // h broadcast buffer (wave-private)
    __shared__ float sPred[RPB][T_DEC];

    const int tid  = (int)threadIdx.x;
    const int w    = tid >> 6;     // wave id = row within block
    const int lane = tid & 63;     // hidden unit
    const int row0 = (int)blockIdx.x * RPB;

    // ---- stage inputs, repacking to padded strides ----
    {
        const float* gp = prior + (size_t)row0 * (T_PRIOR * N_FEAT);
        for (int i = tid; i < RPB * T_PRIOR * N_FEAT; i += 256) {
            int r = i / (T_PRIOR * N_FEAT);
            int rem = i - r * (T_PRIOR * N_FEAT);
            int t = rem / N_FEAT, f = rem - t * N_FEAT;
            sPrior[r][t * PF + f] = gp[i];
        }
        // zero the pad column (poisoned LDS could hold NaN; pad*0 must be 0)
        for (int i = tid; i < RPB * T_PRIOR; i += 256) {
            int r = i / T_PRIOR, t = i - r * T_PRIOR;
            sPrior[r][t * PF + 11] = 0.0f;
        }
        const float* gt = teacher + (size_t)row0 * (T_DEC * DEC_FEAT);
        for (int i = tid; i < RPB * T_DEC * DEC_FEAT; i += 256) {
            int r = i / (T_DEC * DEC_FEAT);
            int rem = i - r * (T_DEC * DEC_FEAT);
            int t = rem / DEC_FEAT, f = rem - t * DEC_FEAT;
            sTeach[r][t * TF + f] = gt[i];
        }
    }
    __syncthreads();

    // ---- encoder weights into VGPRs ----
    float4 whh[3][16];
#pragma unroll
    for (int g = 0; g < 3; ++g) {
        const float4* wr = (const float4*)(eWhh + (size_t)(g * HID + lane) * HID);
#pragma unroll
        for (int k = 0; k < 16; ++k) whh[g][k] = wr[k];
    }
    float4 wih[3][3];
#pragma unroll
    for (int g = 0; g < 3; ++g) {
        const float* wr = eWih + (size_t)(g * HID + lane) * N_FEAT;
        wih[g][0] = make_float4(wr[0], wr[1], wr[2], wr[3]);
        wih[g][1] = make_float4(wr[4], wr[5], wr[6], wr[7]);
        wih[g][2] = make_float4(wr[8], wr[9], wr[10], 0.0f);   // pad weight = 0
    }
    float br  = eBih[lane] + eBhh[lane];
    float bz  = eBih[HID + lane] + eBhh[HID + lane];
    float biN = eBih[2 * HID + lane];
    float bhN = eBhh[2 * HID + lane];

    float h = 0.0f;
    const float4* hb = (const float4*)(&sH[w][0]);

    // ---- encoder: 168 steps ----
    for (int t = 0; t < T_PRIOR; ++t) {
        sH[w][lane] = h;                       // publish (wave-private, no barrier)
        const float4* xb = (const float4*)(&sPrior[w][t * PF]);
        float4 x0 = xb[0], x1 = xb[1], x2 = xb[2];
        float aR = br, aZ = bz, aIN = biN, aHN = bhN;
        aR  = dot4(wih[0][0], x0, aR);  aR  = dot4(wih[0][1], x1, aR);  aR  = dot4(wih[0][2], x2, aR);
        aZ  = dot4(wih[1][0], x0, aZ);  aZ  = dot4(wih[1][1], x1, aZ);  aZ  = dot4(wih[1][2], x2, aZ);
        aIN = dot4(wih[2][0], x0, aIN); aIN = dot4(wih[2][1], x1, aIN); aIN = dot4(wih[2][2], x2, aIN);
#pragma unroll
        for (int k = 0; k < 16; ++k) {
            float4 hv = hb[k];                 // uniform broadcast read
            aR  = dot4(whh[0][k], hv, aR);
            aZ  = dot4(whh[1][k], hv, aZ);
            aHN = dot4(whh[2][k], hv, aHN);
        }
        float r = sigm(aR), z = sigm(aZ);
        float n = tanhfast(fmaf(r, aHN, aIN));
        h = fmaf(z, h - n, n);                 // (1-z)*n + z*h
    }

    // ---- decoder weights (reuse registers) ----
#pragma unroll
    for (int g = 0; g < 3; ++g) {
        const float4* wr = (const float4*)(dWhh + (size_t)(g * HID + lane) * HID);
#pragma unroll
        for (int k = 0; k < 16; ++k) whh[g][k] = wr[k];
    }
    float4 wihD[3][2];
#pragma unroll
    for (int g = 0; g < 3; ++g) {
        const float* wr = dWih + (size_t)(g * HID + lane) * DEC_FEAT;
        wihD[g][0] = make_float4(wr[0], wr[1], wr[2], wr[3]);
        wihD[g][1] = make_float4(wr[4], wr[5], wr[6], 0.0f);   // pad weight = 0
    }
    br  = dBih[lane] + dBhh[lane];
    bz  = dBih[HID + lane] + dBhh[HID + lane];
    biN = dBih[2 * HID + lane];
    bhN = dBhh[2 * HID + lane];
    const float fw = fcW[lane];
    const float fb = fcB[0];

    // x0 = teacher_seq[:, 0, :]
    float4 xq0 = make_float4(sTeach[w][0], sTeach[w][1], sTeach[w][2], sTeach[w][3]);
    float4 xq1 = make_float4(sTeach[w][4], sTeach[w][5], sTeach[w][6], 0.0f);

    // ---- decoder: 48 steps ----
    for (int t = 0; t < T_DEC; ++t) {
        sH[w][lane] = h;
        float aR = br, aZ = bz, aIN = biN, aHN = bhN;
        aR  = dot4(wihD[0][0], xq0, aR);  aR  = dot4(wihD[0][1], xq1, aR);
        aZ  = dot4(wihD[1][0], xq0, aZ);  aZ  = dot4(wihD[1][1], xq1, aZ);
        aIN = dot4(wihD[2][0], xq0, aIN); aIN = dot4(wihD[2][1], xq1, aIN);
#pragma unroll
        for (int k = 0; k < 16; ++k) {
            float4 hv = hb[k];
            aR  = dot4(whh[0][k], hv, aR);
            aZ  = dot4(whh[1][k], hv, aZ);
            aHN = dot4(whh[2][k], hv, aHN);
        }
        float r = sigm(aR), z = sigm(aZ);
        float n = tanhfast(fmaf(r, aHN, aIN));
        h = fmaf(z, h - n, n);

        // pred = h @ fc_W.T + fc_b  (full-wave reduction, result uniform)
        float p = h * fw;
#pragma unroll
        for (int off = 32; off >= 1; off >>= 1) p += __shfl_xor(p, off, 64);
        float pred = p + fb;
        if (lane == 0) sPred[w][t] = pred;

        // next x = [tn[0:4], pred, tn[5:7]], tn = teacher[:, t+1, :]
        if (t < T_DEC - 1) {
            const float* tb = &sTeach[w][(t + 1) * TF];
            xq0 = *(const float4*)tb;                            // f0..f3
            xq1 = make_float4(pred, tb[5], tb[6], 0.0f);         // f4 = pred
        }
    }

    __syncthreads();
    // out shape (B, T_DEC)
    for (int i = tid; i < RPB * T_DEC; i += 256) {
        int w2 = i / T_DEC, t2 = i - w2 * T_DEC;
        out[(size_t)(row0 + w2) * T_DEC + t2] = sPred[w2][t2];
    }
}

extern "C" void kernel_launch(void* const* d_in, const int* in_sizes, int n_in,
                              void* d_out, int out_size, void* d_ws, size_t ws_size,
                              hipStream_t stream)
{
    const float* prior   = (const float*)d_in[0];
    const float* teacher = (const float*)d_in[1];
    const float* eWih    = (const float*)d_in[2];
    const float* eWhh    = (const float*)d_in[3];
    const float* eBih    = (const float*)d_in[4];
    const float* eBhh    = (const float*)d_in[5];
    const float* dWih    = (const float*)d_in[6];
    const float* dWhh    = (const float*)d_in[7];
    const float* dBih    = (const float*)d_in[8];
    const float* dBhh    = (const float*)d_in[9];
    const float* fcW     = (const float*)d_in[10];
    const float* fcB     = (const float*)d_in[11];
    float* out = (float*)d_out;

    dim3 grid(BATCH / RPB);   // 2048 blocks
    dim3 block(256);
    hipLaunchKernelGGL(gru_seq2seq, grid, block, 0, stream,
                       prior, teacher, eWih, eWhh, eBih, eBhh,
                       dWih, dWhh, dBih, dBhh, fcW, fcB, out);
}

// Round 3
// 595.222 us; speedup vs baseline: 2.4664x; 1.3334x over previous
//
#include <hip/hip_runtime.h>

#define T_PRIOR 168
#define N_FEAT 11
#define DEC_FEAT 7
#define HID 64
#define T_DEC 48
#define BATCH 8192

typedef __attribute__((ext_vector_type(8))) short short8;
typedef __attribute__((ext_vector_type(4))) float f32x4;

#define MFMA __builtin_amdgcn_mfma_f32_16x16x32_bf16

__device__ __forceinline__ float sigm(float x) { return 1.0f / (1.0f + __expf(-x)); }
__device__ __forceinline__ float tanhfast(float x) { return 2.0f / (1.0f + __expf(-2.0f * x)) - 1.0f; }

__device__ __forceinline__ unsigned fbits(float f) { union { float f; unsigned u; } v; v.f = f; return v.u; }
__device__ __forceinline__ float bitsf(unsigned u) { union { unsigned u; float f; } v; v.u = u; return v.f; }
// round-to-nearest-even f32 -> bf16 (finite inputs)
__device__ __forceinline__ unsigned short bf16rne(float f) {
    unsigned u = fbits(f);
    return (unsigned short)((u + 0x7fffu + ((u >> 16) & 1u)) >> 16);
}

__global__ __launch_bounds__(64) __attribute__((amdgpu_waves_per_eu(1, 1)))
void gru_mfma(const float* __restrict__ prior, const float* __restrict__ teacher,
              const float* __restrict__ eWih, const float* __restrict__ eWhh,
              const float* __restrict__ eBih, const float* __restrict__ eBhh,
              const float* __restrict__ dWih, const float* __restrict__ dWhh,
              const float* __restrict__ dBih, const float* __restrict__ dBhh,
              const float* __restrict__ fcW, const float* __restrict__ fcB,
              float* __restrict__ out)
{
    // wave-private LDS: h bounce (hi at 0..2047, lo at 2048..4095), swizzled
    __shared__ __align__(16) unsigned sH[1024];
    __shared__ float sPredFB[16];

    const int lane = (int)threadIdx.x;
    const int c = lane & 15;       // C col / A row / B col
    const int g = lane >> 4;       // k-group
    const int row0 = (int)blockIdx.x * 16;

    // ---- persistent per-lane fragments ----
    short8 BHH[3][4][2];   // [gate][u][kt]  Whh^T B-frags, kappa-permuted
    short8 BIH[3][4];      // [gate][u]      Wih^T B-frags (K padded to 32)
    f32x4 bfR[4], bfZ[4], bfIN[4], bfHN[4];
    float h[4][4];         // h state, C layout: [q(row)][u(unit tile)]

#pragma unroll
    for (int q = 0; q < 4; ++q)
#pragma unroll
        for (int u = 0; u < 4; ++u) h[q][u] = 0.0f;

    auto loadPhase = [&](const float* Wih, const float* Whh,
                         const float* bih, const float* bhh, int kvalid) {
#pragma unroll
        for (int gate = 0; gate < 3; ++gate) {
#pragma unroll
            for (int u = 0; u < 4; ++u) {
                const int rw = gate * 64 + u * 16 + c;   // weight row (output unit)
                union { short8 v; unsigned short s[8]; } fi;
#pragma unroll
                for (int j = 0; j < 8; ++j) {
                    int k = g * 8 + j;
                    fi.s[j] = (k < kvalid) ? bf16rne(Wih[rw * kvalid + k]) : (unsigned short)0;
                }
                BIH[gate][u] = fi.v;
#pragma unroll
                for (int kt = 0; kt < 2; ++kt) {
                    union { short8 v; unsigned short s[8]; } fh;
#pragma unroll
                    for (int j = 0; j < 8; ++j) {
                        int kap = kt * 32 + g * 8 + j;                 // permuted k index
                        int unit = ((kap & 3) << 4) | (kap >> 2);      // unit(kappa)
                        fh.s[j] = bf16rne(Whh[rw * 64 + unit]);
                    }
                    BHH[gate][u][kt] = fh.v;
                }
            }
        }
#pragma unroll
        for (int u = 0; u < 4; ++u) {
            const int unit = u * 16 + c;
            float bR = bih[unit] + bhh[unit];
            float bZ = bih[64 + unit] + bhh[64 + unit];
            float bI = bih[128 + unit];
            float bH = bhh[128 + unit];
            bfR[u]  = (f32x4){bR, bR, bR, bR};
            bfZ[u]  = (f32x4){bZ, bZ, bZ, bZ};
            bfIN[u] = (f32x4){bI, bI, bI, bI};
            bfHN[u] = (f32x4){bH, bH, bH, bH};
        }
    };

    // split 8 floats into hi/lo bf16 A-fragments (k = g*8+j)
    auto packsplit = [&](const float (&xv)[8], short8& xh, short8& xl) {
        union { short8 v; unsigned w[4]; } uh, ul;
#pragma unroll
        for (int p = 0; p < 4; ++p) {
            float a = xv[2 * p], b = xv[2 * p + 1];
            unsigned ba = fbits(a), bb = fbits(b);
            unsigned ha = ba & 0xffff0000u, hb = bb & 0xffff0000u;
            float la = a - bitsf(ha), lb = b - bitsf(hb);
            uh.w[p] = (ba >> 16) | hb;
            ul.w[p] = (fbits(la) >> 16) | (fbits(lb) & 0xffff0000u);
        }
        xh = uh.v; xl = ul.v;
    };

    // one GRU step: publish h, read A_h frags, MFMA, gates, update h
    auto gru_step = [&](short8 xhi, short8 xlo) {
        // --- publish h (hi/lo split, kappa layout, swizzled) ---
#pragma unroll
        for (int q = 0; q < 4; ++q) {
            const int r = g * 4 + q;
            unsigned b0 = fbits(h[q][0]), b1 = fbits(h[q][1]);
            unsigned b2 = fbits(h[q][2]), b3 = fbits(h[q][3]);
            unsigned h0 = b0 & 0xffff0000u, h1 = b1 & 0xffff0000u;
            unsigned h2 = b2 & 0xffff0000u, h3 = b3 & 0xffff0000u;
            float l0 = h[q][0] - bitsf(h0), l1 = h[q][1] - bitsf(h1);
            float l2 = h[q][2] - bitsf(h2), l3 = h[q][3] - bitsf(h3);
            unsigned hw0 = (b0 >> 16) | h1;
            unsigned hw1 = (b2 >> 16) | h3;
            unsigned lw0 = (fbits(l0) >> 16) | (fbits(l1) & 0xffff0000u);
            unsigned lw1 = (fbits(l2) >> 16) | (fbits(l3) & 0xffff0000u);
            const unsigned ba = (unsigned)(r * 128) + (((unsigned)(c * 8)) ^ ((unsigned)(r & 7) << 4));
            *(unsigned long long*)((char*)sH + ba) =
                ((unsigned long long)hw1 << 32) | hw0;
            *(unsigned long long*)((char*)sH + 2048 + ba) =
                ((unsigned long long)lw1 << 32) | lw0;
        }
        // --- read A_h fragments (row = c) ---
        const unsigned rb = (unsigned)(c * 128);
        const unsigned sw = (unsigned)(c & 7) << 4;
        short8 a0h = *(const short8*)((char*)sH + (rb + (((unsigned)(g * 16)) ^ sw)));
        short8 a1h = *(const short8*)((char*)sH + (rb + (((unsigned)(64 + g * 16)) ^ sw)));
        short8 a0l = *(const short8*)((char*)sH + 2048 + (rb + (((unsigned)(g * 16)) ^ sw)));
        short8 a1l = *(const short8*)((char*)sH + 2048 + (rb + (((unsigned)(64 + g * 16)) ^ sw)));

        f32x4 aR[4], aZ[4], aIN[4], aHN[4];
#pragma unroll
        for (int u = 0; u < 4; ++u) {
            // r gate: bias C-in on first hh MFMA; x MFMAs last (prefetch slack)
            f32x4 acc = MFMA(a0h, BHH[0][u][0], bfR[u], 0, 0, 0);
            acc = MFMA(a0l, BHH[0][u][0], acc, 0, 0, 0);
            acc = MFMA(a1h, BHH[0][u][1], acc, 0, 0, 0);
            acc = MFMA(a1l, BHH[0][u][1], acc, 0, 0, 0);
            acc = MFMA(xhi, BIH[0][u], acc, 0, 0, 0);
            acc = MFMA(xlo, BIH[0][u], acc, 0, 0, 0);
            aR[u] = acc;
            // z gate
            acc = MFMA(a0h, BHH[1][u][0], bfZ[u], 0, 0, 0);
            acc = MFMA(a0l, BHH[1][u][0], acc, 0, 0, 0);
            acc = MFMA(a1h, BHH[1][u][1], acc, 0, 0, 0);
            acc = MFMA(a1l, BHH[1][u][1], acc, 0, 0, 0);
            acc = MFMA(xhi, BIH[1][u], acc, 0, 0, 0);
            acc = MFMA(xlo, BIH[1][u], acc, 0, 0, 0);
            aZ[u] = acc;
            // h_n (h-part of n gate)
            acc = MFMA(a0h, BHH[2][u][0], bfHN[u], 0, 0, 0);
            acc = MFMA(a0l, BHH[2][u][0], acc, 0, 0, 0);
            acc = MFMA(a1h, BHH[2][u][1], acc, 0, 0, 0);
            acc = MFMA(a1l, BHH[2][u][1], acc, 0, 0, 0);
            aHN[u] = acc;
            // i_n (x-part of n gate)
            acc = MFMA(xhi, BIH[2][u], bfIN[u], 0, 0, 0);
            acc = MFMA(xlo, BIH[2][u], acc, 0, 0, 0);
            aIN[u] = acc;
        }
        // --- gates (elementwise, fp32) ---
#pragma unroll
        for (int u = 0; u < 4; ++u) {
#pragma unroll
            for (int q = 0; q < 4; ++q) {
                float rr = sigm(aR[u][q]);
                float zz = sigm(aZ[u][q]);
                float nn = tanhfast(fmaf(rr, aHN[u][q], aIN[u][q]));
                h[q][u] = nn + zz * (h[q][u] - nn);
            }
        }
    };

    // ================= encoder =================
    loadPhase(eWih, eWhh, eBih, eBhh, N_FEAT);
    const float* prow = prior + (size_t)(row0 + c) * (T_PRIOR * N_FEAT);

    float xc[8] = {0, 0, 0, 0, 0, 0, 0, 0};
    if (g == 0) {
#pragma unroll
        for (int j = 0; j < 8; ++j) xc[j] = prow[j];
    } else if (g == 1) {
#pragma unroll
        for (int j = 0; j < 3; ++j) xc[j] = prow[8 + j];
    }
    for (int t = 0; t < T_PRIOR; ++t) {
        float xn[8] = {0, 0, 0, 0, 0, 0, 0, 0};
        if (t < T_PRIOR - 1) {          // prefetch next step's x
            if (g == 0) {
#pragma unroll
                for (int j = 0; j < 8; ++j) xn[j] = prow[(t + 1) * N_FEAT + j];
            } else if (g == 1) {
#pragma unroll
                for (int j = 0; j < 3; ++j) xn[j] = prow[(t + 1) * N_FEAT + 8 + j];
            }
        }
        short8 xhi, xlo;
        packsplit(xc, xhi, xlo);
        gru_step(xhi, xlo);
#pragma unroll
        for (int j = 0; j < 8; ++j) xc[j] = xn[j];
    }

    // ================= decoder =================
    loadPhase(dWih, dWhh, dBih, dBhh, DEC_FEAT);
    float fw[4];
#pragma unroll
    for (int u = 0; u < 4; ++u) fw[u] = fcW[u * 16 + c];
    const float fb = fcB[0];
    const float* trow = teacher + (size_t)(row0 + c) * (T_DEC * DEC_FEAT);

    float dc[8] = {0, 0, 0, 0, 0, 0, 0, 0};
    if (g == 0) {
#pragma unroll
        for (int j = 0; j < 7; ++j) dc[j] = trow[j];     // x0 = teacher[:,0,:]
    }
    for (int i = 0; i < T_DEC; ++i) {
        float dn[8] = {0, 0, 0, 0, 0, 0, 0, 0};
        if (i < T_DEC - 1 && g == 0) {                   // prefetch teacher feats
#pragma unroll
            for (int j = 0; j < 7; ++j) dn[j] = trow[(i + 1) * DEC_FEAT + j];
        }
        if (i > 0 && g == 0) dc[4] = sPredFB[c];         // autoregressive feat 4
        short8 xhi, xlo;
        packsplit(dc, xhi, xlo);
        gru_step(xhi, xlo);

        // pred = h @ fcW + fb, reduce over c within each 16-lane group
#pragma unroll
        for (int q = 0; q < 4; ++q) {
            float p = fmaf(h[q][0], fw[0],
                      fmaf(h[q][1], fw[1],
                      fmaf(h[q][2], fw[2], h[q][3] * fw[3])));
            p += __shfl_xor(p, 1, 64);
            p += __shfl_xor(p, 2, 64);
            p += __shfl_xor(p, 4, 64);
            p += __shfl_xor(p, 8, 64);
            p += fb;
            if (c == q) {
                out[(size_t)(row0 + g * 4 + q) * T_DEC + i] = p;
                sPredFB[g * 4 + q] = p;
            }
        }
#pragma unroll
        for (int j = 0; j < 8; ++j) dc[j] = dn[j];
    }
}

extern "C" void kernel_launch(void* const* d_in, const int* in_sizes, int n_in,
                              void* d_out, int out_size, void* d_ws, size_t ws_size,
                              hipStream_t stream)
{
    const float* prior   = (const float*)d_in[0];
    const float* teacher = (const float*)d_in[1];
    const float* eWih    = (const float*)d_in[2];
    const float* eWhh    = (const float*)d_in[3];
    const float* eBih    = (const float*)d_in[4];
    const float* eBhh    = (const float*)d_in[5];
    const float* dWih    = (const float*)d_in[6];
    const float* dWhh    = (const float*)d_in[7];
    const float* dBih    = (const float*)d_in[8];
    const float* dBhh    = (const float*)d_in[9];
    const float* fcW     = (const float*)d_in[10];
    const float* fcB     = (const float*)d_in[11];
    float* out = (float*)d_out;

    dim3 grid(BATCH / 16);   // 512 blocks, 1 wave each (16 batch rows per wave)
    dim3 block(64);
    hipLaunchKernelGGL(gru_mfma, grid, block, 0, stream,
                       prior, teacher, eWih, eWhh, eBih, eBhh,
                       dWih, dWhh, dBih, dBhh, fcW, fcB, out);
}

// Round 4
// 306.091 us; speedup vs baseline: 4.7961x; 1.9446x over previous
//
#include <hip/hip_runtime.h>

#define T_PRIOR 168
#define N_FEAT 11
#define DEC_FEAT 7
#define HID 64
#define T_DEC 48
#define BATCH 8192

typedef __attribute__((ext_vector_type(8))) short short8;
typedef __attribute__((ext_vector_type(4))) float f32x4;

#define MFMA __builtin_amdgcn_mfma_f32_16x16x32_bf16

__device__ __forceinline__ float sigm(float x) { return 1.0f / (1.0f + __expf(-x)); }
__device__ __forceinline__ float tanhfast(float x) { return 2.0f / (1.0f + __expf(-2.0f * x)) - 1.0f; }
__device__ __forceinline__ unsigned fbits(float f) { union { float f; unsigned u; } v; v.f = f; return v.u; }
__device__ __forceinline__ float bitsf(unsigned u) { union { unsigned u; float f; } v; v.u = u; return v.f; }
__device__ __forceinline__ unsigned short bf16rne(float f) {
    unsigned u = fbits(f);
    return (unsigned short)((u + 0x7fffu + ((u >> 16) & 1u)) >> 16);
}

__global__ __launch_bounds__(256) __attribute__((amdgpu_waves_per_eu(2)))
void gru_mfma(const float* __restrict__ prior, const float* __restrict__ teacher,
              const float* __restrict__ eWih, const float* __restrict__ eWhh,
              const float* __restrict__ eBih, const float* __restrict__ eBhh,
              const float* __restrict__ dWih, const float* __restrict__ dWhh,
              const float* __restrict__ dBih, const float* __restrict__ dBhh,
              const float* __restrict__ fcW, const float* __restrict__ fcB,
              float* __restrict__ out)
{
    // block-shared h bounce: [parity][hi/lo][16 rows x 64 kappa] bf16, XOR-swizzled
    __shared__ __align__(16) unsigned short sH[2][2][1024];
    __shared__ float sPartial[2][4][16];   // [parity][wave][row]

    const int tid  = (int)threadIdx.x;
    const int lane = tid & 63;
    const int w    = tid >> 6;     // wave id = unit tile u (0..3)
    const int c    = lane & 15;    // A row / B col / C col
    const int g    = lane >> 4;    // k-group
    const int row0 = (int)blockIdx.x * 16;

    // ---- per-wave persistent fragments (unit tile w only) ----
    short8 BHH[3][2];   // [gate][kt] Whh^T B-frags, kappa-permuted
    short8 BIH[3];      // [gate]     Wih^T B-frags (K padded to 32)
    f32x4 bR4, bZ4, bI4, bH4;

    auto loadPhase = [&](const float* Wih, const float* Whh,
                         const float* bih, const float* bhh, int kvalid) {
        const int rw_base = w * 16 + c;
#pragma unroll
        for (int gate = 0; gate < 3; ++gate) {
            const int rw = gate * 64 + rw_base;      // weight row (output unit)
            union { short8 v; unsigned short s[8]; } fi;
#pragma unroll
            for (int j = 0; j < 8; ++j) {
                int k = g * 8 + j;
                fi.s[j] = (k < kvalid) ? bf16rne(Wih[rw * kvalid + k]) : (unsigned short)0;
            }
            BIH[gate] = fi.v;
#pragma unroll
            for (int kt = 0; kt < 2; ++kt) {
                union { short8 v; unsigned short s[8]; } fh;
#pragma unroll
                for (int j = 0; j < 8; ++j) {
                    int kap = kt * 32 + g * 8 + j;              // permuted k index
                    int unit = ((kap & 3) << 4) | (kap >> 2);   // unit(kappa)
                    fh.s[j] = bf16rne(Whh[rw * 64 + unit]);
                }
                BHH[gate][kt] = fh.v;
            }
        }
        const int un = w * 16 + c;
        float vR = bih[un] + bhh[un];
        float vZ = bih[64 + un] + bhh[64 + un];
        float vI = bih[128 + un];
        float vH = bhh[128 + un];
        bR4 = (f32x4){vR, vR, vR, vR};
        bZ4 = (f32x4){vZ, vZ, vZ, vZ};
        bI4 = (f32x4){vI, vI, vI, vI};
        bH4 = (f32x4){vH, vH, vH, vH};
    };

    // publish this wave's 16-unit slice of h (hi/lo split, kappa layout, swizzled)
    auto publish = [&](int p, const float (&h)[4]) {
#pragma unroll
        for (int q = 0; q < 4; ++q) {
            const int r = g * 4 + q;
            unsigned hb = fbits(h[q]) & 0xffff0000u;
            unsigned short hi = (unsigned short)(hb >> 16);
            unsigned short lo = (unsigned short)(fbits(h[q] - bitsf(hb)) >> 16);
            const unsigned off = (unsigned)(r * 128) +
                (((unsigned)(c * 8 + w * 2)) ^ (((unsigned)(r & 7)) << 4));
            *(unsigned short*)((char*)&sH[p][0][0] + off) = hi;
            *(unsigned short*)((char*)&sH[p][1][0] + off) = lo;
        }
    };

    // split 8 floats (k = g*8+j) into hi/lo bf16 A-fragments
    auto packsplit = [&](const float (&xv)[8], short8& xh, short8& xl) {
        union { short8 v; unsigned wd[4]; } uh, ul;
#pragma unroll
        for (int pp = 0; pp < 4; ++pp) {
            float a = xv[2 * pp], b = xv[2 * pp + 1];
            unsigned ba = fbits(a), bb = fbits(b);
            unsigned ha = ba & 0xffff0000u, hbv = bb & 0xffff0000u;
            float la = a - bitsf(ha), lb = b - bitsf(hbv);
            uh.wd[pp] = (ba >> 16) | hbv;
            ul.wd[pp] = (fbits(la) >> 16) | (fbits(lb) & 0xffff0000u);
        }
        xh = uh.v; xl = ul.v;
    };

    // one GRU step (after barrier): read h frags, 18 MFMAs, gates
    auto gru_step = [&](int p, short8 xhi, short8 xlo, float (&h)[4]) {
        const unsigned swz = ((unsigned)(c & 7)) << 4;
        const unsigned b0 = (unsigned)(c * 128) + (((unsigned)(g * 16)) ^ swz);
        const unsigned b1 = (unsigned)(c * 128) + (((unsigned)(64 + g * 16)) ^ swz);
        short8 a0h = *(const short8*)((const char*)&sH[p][0][0] + b0);
        short8 a1h = *(const short8*)((const char*)&sH[p][0][0] + b1);
        short8 a0l = *(const short8*)((const char*)&sH[p][1][0] + b0);
        short8 a1l = *(const short8*)((const char*)&sH[p][1][0] + b1);

        f32x4 accR = MFMA(a0h, BHH[0][0], bR4, 0, 0, 0);
        accR = MFMA(a0l, BHH[0][0], accR, 0, 0, 0);
        accR = MFMA(a1h, BHH[0][1], accR, 0, 0, 0);
        accR = MFMA(a1l, BHH[0][1], accR, 0, 0, 0);
        accR = MFMA(xhi, BIH[0], accR, 0, 0, 0);
        accR = MFMA(xlo, BIH[0], accR, 0, 0, 0);

        f32x4 accZ = MFMA(a0h, BHH[1][0], bZ4, 0, 0, 0);
        accZ = MFMA(a0l, BHH[1][0], accZ, 0, 0, 0);
        accZ = MFMA(a1h, BHH[1][1], accZ, 0, 0, 0);
        accZ = MFMA(a1l, BHH[1][1], accZ, 0, 0, 0);
        accZ = MFMA(xhi, BIH[1], accZ, 0, 0, 0);
        accZ = MFMA(xlo, BIH[1], accZ, 0, 0, 0);

        f32x4 accH = MFMA(a0h, BHH[2][0], bH4, 0, 0, 0);
        accH = MFMA(a0l, BHH[2][0], accH, 0, 0, 0);
        accH = MFMA(a1h, BHH[2][1], accH, 0, 0, 0);
        accH = MFMA(a1l, BHH[2][1], accH, 0, 0, 0);

        f32x4 accI = MFMA(xhi, BIH[2], bI4, 0, 0, 0);
        accI = MFMA(xlo, BIH[2], accI, 0, 0, 0);

#pragma unroll
        for (int q = 0; q < 4; ++q) {
            float rr = sigm(accR[q]);
            float zz = sigm(accZ[q]);
            float nn = tanhfast(fmaf(rr, accH[q], accI[q]));
            h[q] = nn + zz * (h[q] - nn);
        }
    };

    float h[4] = {0.0f, 0.0f, 0.0f, 0.0f};

    // ================= encoder =================
    loadPhase(eWih, eWhh, eBih, eBhh, N_FEAT);
    const float* prow = prior + (size_t)(row0 + c) * (T_PRIOR * N_FEAT);

    float xc[8] = {0, 0, 0, 0, 0, 0, 0, 0};
    if (g == 0) {
#pragma unroll
        for (int j = 0; j < 8; ++j) xc[j] = prow[j];
    } else if (g == 1) {
#pragma unroll
        for (int j = 0; j < 3; ++j) xc[j] = prow[8 + j];
    }
    for (int t = 0; t < T_PRIOR; ++t) {
        const int p = t & 1;
        publish(p, h);
        float xn[8] = {0, 0, 0, 0, 0, 0, 0, 0};
        if (t < T_PRIOR - 1) {               // prefetch next x (covers global latency)
            if (g == 0) {
#pragma unroll
                for (int j = 0; j < 8; ++j) xn[j] = prow[(t + 1) * N_FEAT + j];
            } else if (g == 1) {
#pragma unroll
                for (int j = 0; j < 3; ++j) xn[j] = prow[(t + 1) * N_FEAT + 8 + j];
            }
        }
        short8 xhi, xlo;
        packsplit(xc, xhi, xlo);
        __syncthreads();
        gru_step(p, xhi, xlo, h);
#pragma unroll
        for (int j = 0; j < 8; ++j) xc[j] = xn[j];
    }

    // ================= decoder =================
    loadPhase(dWih, dWhh, dBih, dBhh, DEC_FEAT);
    const float fwc = fcW[w * 16 + c];
    const float fb  = fcB[0];
    const float* trow = teacher + (size_t)(row0 + c) * (T_DEC * DEC_FEAT);

    float dc[8] = {0, 0, 0, 0, 0, 0, 0, 0};
    if (g == 0) {
#pragma unroll
        for (int j = 0; j < 7; ++j) dc[j] = trow[j];     // x0 = teacher[:,0,:]
    }
    for (int i = 0; i < T_DEC; ++i) {
        const int p = i & 1;                 // (168+i)&1 == i&1
        publish(p, h);
        float dn[8] = {0, 0, 0, 0, 0, 0, 0, 0};
        if (i < T_DEC - 1 && g == 0) {
#pragma unroll
            for (int j = 0; j < 7; ++j) dn[j] = trow[(i + 1) * DEC_FEAT + j];
        }
        __syncthreads();
        if (i > 0) {                         // pred_{i-1} from parity-(i-1) partials
            const int b = (i - 1) & 1;
            float pred = sPartial[b][0][c] + sPartial[b][1][c] +
                         sPartial[b][2][c] + sPartial[b][3][c] + fb;
            if (g == 0) dc[4] = pred;        // autoregressive feature 4
            if (w == 0 && lane < 16)
                out[(size_t)(row0 + lane) * T_DEC + (i - 1)] = pred;
        }
        short8 xhi, xlo;
        packsplit(dc, xhi, xlo);
        gru_step(p, xhi, xlo, h);

        // fc partials of h_i over this wave's 16 units
#pragma unroll
        for (int q = 0; q < 4; ++q) {
            float v = h[q] * fwc;
            v += __shfl_xor(v, 1, 64);
            v += __shfl_xor(v, 2, 64);
            v += __shfl_xor(v, 4, 64);
            v += __shfl_xor(v, 8, 64);
            if (c == 0) sPartial[i & 1][w][g * 4 + q] = v;
        }
#pragma unroll
        for (int j = 0; j < 8; ++j) dc[j] = dn[j];
    }
    __syncthreads();
    {
        const int b = (T_DEC - 1) & 1;
        float pred = sPartial[b][0][c] + sPartial[b][1][c] +
                     sPartial[b][2][c] + sPartial[b][3][c] + fb;
        if (w == 0 && lane < 16)
            out[(size_t)(row0 + lane) * T_DEC + (T_DEC - 1)] = pred;
    }
}

extern "C" void kernel_launch(void* const* d_in, const int* in_sizes, int n_in,
                              void* d_out, int out_size, void* d_ws, size_t ws_size,
                              hipStream_t stream)
{
    const float* prior   = (const float*)d_in[0];
    const float* teacher = (const float*)d_in[1];
    const float* eWih    = (const float*)d_in[2];
    const float* eWhh    = (const float*)d_in[3];
    const float* eBih    = (const float*)d_in[4];
    const float* eBhh    = (const float*)d_in[5];
    const float* dWih    = (const float*)d_in[6];
    const float* dWhh    = (const float*)d_in[7];
    const float* dBih    = (const float*)d_in[8];
    const float* dBhh    = (const float*)d_in[9];
    const float* fcW     = (const float*)d_in[10];
    const float* fcB     = (const float*)d_in[11];
    float* out = (float*)d_out;

    dim3 grid(BATCH / 16);    // 512 blocks x 4 waves = 2048 waves (2/SIMD)
    dim3 block(256);
    hipLaunchKernelGGL(gru_mfma, grid, block, 0, stream,
                       prior, teacher, eWih, eWhh, eBih, eBhh,
                       dWih, dWhh, dBih, dBhh, fcW, fcB, out);
}